// Round 1
// baseline (779.745 us; speedup 1.0000x reference)
//
#include <hip/hip_runtime.h>

// Problem constants (fixed by the reference)
constexpr int B = 32, S = 2048, D = 1024, N = 256;

#define DEV __device__ __forceinline__

// ---- DPP wave-64 reduction helpers -------------------------------------
// row_shr:N = 0x110|N, row_bcast15 = 0x142, row_bcast31 = 0x143.
// bound_ctrl=1 -> invalid source lanes contribute 0. Total lands in lane 63.
template <int CTRL>
DEV float dpp_add(float x) {
  int y = __builtin_amdgcn_update_dpp(0, __float_as_int(x), CTRL, 0xF, 0xF, true);
  return x + __int_as_float(y);
}

DEV void wave_reduce3(float& a, float& b, float& c) {
  a = dpp_add<0x111>(a); b = dpp_add<0x111>(b); c = dpp_add<0x111>(c);
  a = dpp_add<0x112>(a); b = dpp_add<0x112>(b); c = dpp_add<0x112>(c);
  a = dpp_add<0x114>(a); b = dpp_add<0x114>(b); c = dpp_add<0x114>(c);
  a = dpp_add<0x118>(a); b = dpp_add<0x118>(b); c = dpp_add<0x118>(c);
  a = dpp_add<0x142>(a); b = dpp_add<0x142>(b); c = dpp_add<0x142>(c);
  a = dpp_add<0x143>(a); b = dpp_add<0x143>(b); c = dpp_add<0x143>(c);
  a = __int_as_float(__builtin_amdgcn_readlane(__float_as_int(a), 63));
  b = __int_as_float(__builtin_amdgcn_readlane(__float_as_int(b), 63));
  c = __int_as_float(__builtin_amdgcn_readlane(__float_as_int(c), 63));
}

// ---- Kernel 1: u[b,s] = mean_d x[b,s,d] --------------------------------
__global__ __launch_bounds__(256) void mean_kernel(const float4* __restrict__ x4,
                                                   float* __restrict__ u) {
  const int wave  = (blockIdx.x * 256 + threadIdx.x) >> 6;
  const int lane  = threadIdx.x & 63;
  const int nwave = gridDim.x * 4;
  for (int row = wave; row < B * S; row += nwave) {
    const float4* xr = x4 + (size_t)row * (D / 4);
    float s = 0.f;
#pragma unroll
    for (int j = 0; j < 4; ++j) {
      float4 v = xr[lane + 64 * j];
      s += (v.x + v.y) + (v.z + v.w);
    }
#pragma unroll
    for (int off = 32; off; off >>= 1) s += __shfl_xor(s, off, 64);
    if (lane == 0) u[row] = s * (1.f / 1024.f);
  }
}

// ---- Kernel 2: sequential scan, one wave per batch ---------------------
__global__ __launch_bounds__(64) void scan_kernel(
    const float* __restrict__ u, const float* __restrict__ llr,
    const float* __restrict__ logb, const float* __restrict__ c,
    const float* __restrict__ lstep, const float* __restrict__ gma,
    const float* __restrict__ bta, float* __restrict__ sout) {
  const int b    = blockIdx.x;
  const int lane = threadIdx.x;
  const float stp = expf(lstep[0]);

  float ad[4], bdc[4], gm[4], bt[4], gc[4];
  float Gp = 0.f, BCp = 0.f, dummy = 0.f;
#pragma unroll
  for (int k = 0; k < 4; ++k) {
    const int n = lane * 4 + k;
    const float lam = -expf(llr[n]);
    const float sl  = stp * lam;
    ad[k]  = (2.f + sl) / (2.f - sl);
    bdc[k] = stp * (1.f + ad[k]) * expf(logb[n]) * 0.5f;
    gm[k] = gma[n];
    bt[k] = bta[n];
    const float cc = c[n];
    gc[k] = gm[k] * cc;
    Gp  += gc[k];
    BCp += bt[k] * cc;
  }
  wave_reduce3(Gp, BCp, dummy);
  const float G = Gp, BC = BCp;

  float h0 = 0.f, h1 = 0.f, h2 = 0.f, h3 = 0.f;
  const float* urow = u + b * S;
  float* srow = sout + b * S;

  for (int t0 = 0; t0 < S; t0 += 64) {
    const float uch = urow[t0 + lane];  // 64 timesteps of drive in registers
#pragma unroll 8
    for (int tt = 0; tt < 64; ++tt) {
      const float ut = __int_as_float(
          __builtin_amdgcn_readlane(__float_as_int(uch), tt));
      const float v0 = fmaf(ad[0], h0, bdc[0] * ut);
      const float v1 = fmaf(ad[1], h1, bdc[1] * ut);
      const float v2 = fmaf(ad[2], h2, bdc[2] * ut);
      const float v3 = fmaf(ad[3], h3, bdc[3] * ut);
      float s1 = (v0 + v1) + (v2 + v3);
      float s2 = fmaf(v0, v0, fmaf(v1, v1, fmaf(v2, v2, v3 * v3)));
      float s3 = fmaf(v0, gc[0], fmaf(v1, gc[1], fmaf(v2, gc[2], v3 * gc[3])));
      wave_reduce3(s1, s2, s3);
      const float mu  = s1 * (1.f / 256.f);
      const float var = fmaf(s2, 1.f / 256.f, -mu * mu);
      const float r   = rsqrtf(var + 1e-5f);
      h0 = fmaf((v0 - mu) * r, gm[0], bt[0]);
      h1 = fmaf((v1 - mu) * r, gm[1], bt[1]);
      h2 = fmaf((v2 - mu) * r, gm[2], bt[2]);
      h3 = fmaf((v3 - mu) * r, gm[3], bt[3]);
      const float st = fmaf(r, fmaf(-mu, G, s3), BC);
      if (lane == 0) srow[t0 + tt] = st;
    }
  }
}

// ---- Kernel 3: out = cx*x + cs*s[b,t] ----------------------------------
__global__ __launch_bounds__(256) void out_kernel(
    const float4* __restrict__ x4, const float* __restrict__ s,
    const float* __restrict__ logd, const float* __restrict__ alpha,
    float4* __restrict__ o4) {
  const float asig = 1.f / (1.f + expf(-alpha[0]));
  const float dd   = expf(logd[0]);
  const float cx   = asig + (1.f - asig) * dd;
  const float cs   = 1.f - asig;
  const int i = blockIdx.x * 256 + threadIdx.x;  // exactly B*S*D/4 threads
  const float sv = cs * s[i >> 8];               // 256 float4 per (b,t) row
  const float4 v = x4[i];
  float4 o;
  o.x = fmaf(cx, v.x, sv);
  o.y = fmaf(cx, v.y, sv);
  o.z = fmaf(cx, v.z, sv);
  o.w = fmaf(cx, v.w, sv);
  o4[i] = o;
}

extern "C" void kernel_launch(void* const* d_in, const int* in_sizes, int n_in,
                              void* d_out, int out_size, void* d_ws, size_t ws_size,
                              hipStream_t stream) {
  const float* x     = (const float*)d_in[0];
  const float* llr   = (const float*)d_in[1];
  const float* logb  = (const float*)d_in[2];
  const float* c     = (const float*)d_in[3];
  const float* logd  = (const float*)d_in[4];
  const float* lstep = (const float*)d_in[5];
  const float* alpha = (const float*)d_in[6];
  const float* gma   = (const float*)d_in[7];
  const float* bta   = (const float*)d_in[8];

  float* u = (float*)d_ws;   // B*S floats
  float* s = u + B * S;      // B*S floats

  mean_kernel<<<2048, 256, 0, stream>>>((const float4*)x, u);
  scan_kernel<<<B, 64, 0, stream>>>(u, llr, logb, c, lstep, gma, bta, s);
  out_kernel<<<(B * S * D / 4) / 256, 256, 0, stream>>>(
      (const float4*)x, s, logd, alpha, (float4*)d_out);
}

// Round 2
// 690.364 us; speedup vs baseline: 1.1295x; 1.1295x over previous
//
#include <hip/hip_runtime.h>

// Problem constants (fixed by the reference)
constexpr int B = 32, S = 2048, D = 1024, N = 256;

#define DEV __device__ __forceinline__

// ---- DPP wave-64 reduction helpers -------------------------------------
// row_shr:N = 0x110|N, row_bcast15 = 0x142, row_bcast31 = 0x143.
// bound_ctrl=1 -> invalid source lanes contribute 0. Total lands in lane 63.
template <int CTRL>
DEV float dpp_add(float x) {
  int y = __builtin_amdgcn_update_dpp(0, __float_as_int(x), CTRL, 0xF, 0xF, true);
  return x + __int_as_float(y);
}

DEV float rdlane(float v, int l) {
  return __int_as_float(__builtin_amdgcn_readlane(__float_as_int(v), l));
}

// Reduce 3 independent sums across 64 lanes; results broadcast to ALL lanes
// (via readlane 63 -> SGPR). The 3 chains interleave to hide DPP wait states.
DEV void wave_reduce3(float& a, float& b, float& c) {
  a = dpp_add<0x111>(a); b = dpp_add<0x111>(b); c = dpp_add<0x111>(c);
  a = dpp_add<0x112>(a); b = dpp_add<0x112>(b); c = dpp_add<0x112>(c);
  a = dpp_add<0x114>(a); b = dpp_add<0x114>(b); c = dpp_add<0x114>(c);
  a = dpp_add<0x118>(a); b = dpp_add<0x118>(b); c = dpp_add<0x118>(c);
  a = dpp_add<0x142>(a); b = dpp_add<0x142>(b); c = dpp_add<0x142>(c);
  a = dpp_add<0x143>(a); b = dpp_add<0x143>(b); c = dpp_add<0x143>(c);
  a = rdlane(a, 63);
  b = rdlane(b, 63);
  c = rdlane(c, 63);
}

// ---- Kernel 1: u[b,s] = mean_d x[b,s,d] --------------------------------
// One wave per row; 4 independent float4 loads issue together.
__global__ __launch_bounds__(256) void mean_kernel(const float4* __restrict__ x4,
                                                   float* __restrict__ u) {
  const int row  = (blockIdx.x << 2) | (threadIdx.x >> 6);
  const int lane = threadIdx.x & 63;
  const float4* xr = x4 + (size_t)row * (D / 4);
  float s = 0.f;
#pragma unroll
  for (int j = 0; j < 4; ++j) {
    float4 v = xr[lane + (j << 6)];
    s += (v.x + v.y) + (v.z + v.w);
  }
#pragma unroll
  for (int off = 32; off; off >>= 1) s += __shfl_xor(s, off, 64);
  if (lane == 0) u[row] = s * (1.f / 1024.f);
}

// ---- Kernel 2: sequential scan, one wave per batch ---------------------
// Track the UNNORMALIZED pre-LN state z (LN is scale/shift invariant in a
// folded form):  z_{t+1} = (a*gamma) .* (256*z_t - s1) * r' + (a*beta + b*u)
// with r' = rsqrt(256*s2 - s1^2 + 65536*eps)  ( == r_t / 256 exactly ).
// s_t = r' * (256*s3 - s1*G) + BC, s3 = sum(c*gamma.*z), G = sum(c*gamma),
// BC = sum(c*beta).
__global__ __launch_bounds__(64) void scan_kernel(
    const float* __restrict__ u, const float* __restrict__ llr,
    const float* __restrict__ logb, const float* __restrict__ c,
    const float* __restrict__ lstep, const float* __restrict__ gma,
    const float* __restrict__ bta, float* __restrict__ sout) {
  const int b    = blockIdx.x;
  const int lane = threadIdx.x;
  const float stp = expf(lstep[0]);

  float ag[4], ab[4], bd[4], cg[4];
  float Gp = 0.f, BCp = 0.f, d0 = 0.f;
#pragma unroll
  for (int k = 0; k < 4; ++k) {
    const int n = (k << 6) | lane;            // coalesced param loads
    const float lam = -expf(llr[n]);
    const float sl  = stp * lam;
    const float adisc = (2.f + sl) / (2.f - sl);
    const float bdisc = stp * (1.f + adisc) * expf(logb[n]) * 0.5f;
    const float g  = gma[n];
    const float be = bta[n];
    const float cc = c[n];
    ag[k] = adisc * g;
    ab[k] = adisc * be;
    bd[k] = bdisc;
    cg[k] = cc * g;
    Gp  += cg[k];
    BCp += cc * be;
  }
  wave_reduce3(Gp, BCp, d0);
  const float G = Gp, BC = BCp;
  const float Ceps = 65536.f * 1e-5f;

  const float* urow = u + b * S;
  float* srow = sout + b * S;

  float uch = urow[lane];                      // chunk of 64 timesteps
  const float u0 = rdlane(uch, 0);
  float z0 = bd[0] * u0, z1 = bd[1] * u0, z2 = bd[2] * u0, z3 = bd[3] * u0;

  for (int t0 = 0; t0 < S; t0 += 64) {
    int nx = t0 + 64 + lane;
    if (nx > S - 1) nx = S - 1;                // clamped prefetch (tail unused)
    const float uch_next = urow[nx];
    float stk = 0.f;
#pragma unroll
    for (int tt = 0; tt < 64; ++tt) {
      // three reductions over the 256 states (balanced trees in-lane)
      float s1 = (z0 + z1) + (z2 + z3);
      float s2 = fmaf(z0, z0, z1 * z1) + fmaf(z2, z2, z3 * z3);
      float s3 = fmaf(z0, cg[0], z1 * cg[1]) + fmaf(z2, cg[2], z3 * cg[3]);
      wave_reduce3(s1, s2, s3);
      const float q = fmaf(256.f, s2, fmaf(-s1, s1, Ceps));
      const float r = __builtin_amdgcn_rsqf(q);          // v_rsq_f32
      const float st = fmaf(r, fmaf(256.f, s3, -s1 * G), BC);
      stk = (lane == tt) ? st : stk;           // lane tt keeps step tt's output

      // next drive value (compile-time lane index after unroll)
      const float un = (tt < 63) ? rdlane(uch, tt + 1) : rdlane(uch_next, 0);
      // state update: w and t1 issue while rsq is in flight
      const float w0 = fmaf(256.f, z0, -s1);
      const float w1 = fmaf(256.f, z1, -s1);
      const float w2 = fmaf(256.f, z2, -s1);
      const float w3 = fmaf(256.f, z3, -s1);
      z0 = fmaf(ag[0] * w0, r, fmaf(bd[0], un, ab[0]));
      z1 = fmaf(ag[1] * w1, r, fmaf(bd[1], un, ab[1]));
      z2 = fmaf(ag[2] * w2, r, fmaf(bd[2], un, ab[2]));
      z3 = fmaf(ag[3] * w3, r, fmaf(bd[3], un, ab[3]));
    }
    srow[t0 + lane] = stk;                     // one coalesced store / 64 steps
    uch = uch_next;
  }
}

// ---- Kernel 3: out = cx*x + cs*s[b,t] ----------------------------------
__global__ __launch_bounds__(256) void out_kernel(
    const float4* __restrict__ x4, const float* __restrict__ s,
    const float* __restrict__ logd, const float* __restrict__ alpha,
    float4* __restrict__ o4) {
  const float asig = 1.f / (1.f + expf(-alpha[0]));
  const float dd   = expf(logd[0]);
  const float cx   = asig + (1.f - asig) * dd;
  const float cs   = 1.f - asig;
  const int i = blockIdx.x * 256 + threadIdx.x;  // exactly B*S*D/4 threads
  const float sv = cs * s[i >> 8];               // 256 float4 per (b,t) row
  const float4 v = x4[i];
  float4 o;
  o.x = fmaf(cx, v.x, sv);
  o.y = fmaf(cx, v.y, sv);
  o.z = fmaf(cx, v.z, sv);
  o.w = fmaf(cx, v.w, sv);
  o4[i] = o;
}

extern "C" void kernel_launch(void* const* d_in, const int* in_sizes, int n_in,
                              void* d_out, int out_size, void* d_ws, size_t ws_size,
                              hipStream_t stream) {
  const float* x     = (const float*)d_in[0];
  const float* llr   = (const float*)d_in[1];
  const float* logb  = (const float*)d_in[2];
  const float* c     = (const float*)d_in[3];
  const float* logd  = (const float*)d_in[4];
  const float* lstep = (const float*)d_in[5];
  const float* alpha = (const float*)d_in[6];
  const float* gma   = (const float*)d_in[7];
  const float* bta   = (const float*)d_in[8];

  float* u = (float*)d_ws;   // B*S floats
  float* s = u + B * S;      // B*S floats

  mean_kernel<<<B * S / 4, 256, 0, stream>>>((const float4*)x, u);
  scan_kernel<<<B, 64, 0, stream>>>(u, llr, logb, c, lstep, gma, bta, s);
  out_kernel<<<(B * S * D / 4) / 256, 256, 0, stream>>>(
      (const float4*)x, s, logd, alpha, (float4*)d_out);
}